// Round 9
// baseline (3521.235 us; speedup 1.0000x reference)
//
#include <hip/hip_runtime.h>
#include <cstdint>
#include <cstddef>

// =====================================================================
// RBM Gibbs sampling, bit-exact replication of JAX-on-CPU reference.
// ROUND 8 (perf): k_sample_v rewritten — per-b ballot compaction of the
// ~128 SET h-bits into an ascending LDS offset list; accumulation is a
// direct h-ascending sum over set bits (bit-identical to sequential
// h=0..255 with exact zero-skip). float2 v-pairs per thread, 2 b-groups
// per 512-thread block. Removes the 8g x 1280bit cndmask+add VALU burn.
// Semantics FROZEN (rounds 6-7 passed, absmax=0):
//  - threefry2x32 partitionable; fold-like split; seed(42)->(0,42).
//  - cephes-Horner exp, Pommier-Horner log (q1/q2 tail), no contract.
//  - sigmoid = 1/(1+exp(-x)) IEEE div; gumbel tiny-clamp; first-max
//    argmax; bernoulli u<p; v-GEMM K=256 single sequential chain.
//  - h-GEMM: Eigen gebp kc=320 slab fold, k ascending (c-major).
// =====================================================================

#define B_DIM 16384
#define C_DIM 5
#define H_DIM 256
#define V_DIM 512
#define KC    320   // Eigen MT gebp kc (Zen5 48KB L1d: min(435,320)=320)

struct TFOut { uint32_t a, b; };

__host__ __device__ static inline TFOut tf2x32(uint32_t k0, uint32_t k1,
                                               uint32_t c0, uint32_t c1) {
  uint32_t ks2 = k0 ^ k1 ^ 0x1BD11BDAu;
  uint32_t x0 = c0 + k0, x1 = c1 + k1;
#define TF_R(r) { x0 += x1; x1 = (x1 << r) | (x1 >> (32 - r)); x1 ^= x0; }
  TF_R(13) TF_R(15) TF_R(26) TF_R(6)
  x0 += k1;  x1 += ks2 + 1u;
  TF_R(17) TF_R(29) TF_R(16) TF_R(24)
  x0 += ks2; x1 += k0 + 2u;
  TF_R(13) TF_R(15) TF_R(26) TF_R(6)
  x0 += k0;  x1 += k1 + 3u;
  TF_R(17) TF_R(29) TF_R(16) TF_R(24)
  x0 += k1;  x1 += ks2 + 4u;
  TF_R(13) TF_R(15) TF_R(26) TF_R(6)
  x0 += ks2; x1 += k0 + 5u;
#undef TF_R
  TFOut o; o.a = x0; o.b = x1; return o;
}

// partitionable random_bits, 32-bit width, element index i (< 2^32)
__device__ static inline uint32_t rng_bits(uint32_t k0, uint32_t k1, uint32_t i) {
  TFOut r = tf2x32(k0, k1, 0u, i);
  return r.a ^ r.b;
}

__device__ static inline float bits_to_unit_float(uint32_t bits) {
  return __uint_as_float((bits >> 9) | 0x3F800000u) - 1.0f;
}

// XLA GenerateVF32Exp replica (cephes Horner port), mul+add separate,
// NO contraction.
__device__ static float xla_exp(float x_in) {
#pragma clang fp contract(off)
  float x = fminf(x_in, 88.3762626647950f);
  x = fmaxf(x, -88.3762626647949f);
  float fx = floorf(x * 1.44269504088896341f + 0.5f);
  float tmp = fx * 0.693359375f;
  float z = fx * -2.12194440e-4f;
  x = x - tmp;
  x = x - z;
  z = x * x;
  float y = 1.9875691500e-4f;
  y = y * x + 1.3981999507e-3f;
  y = y * x + 8.3334519073e-3f;
  y = y * x + 4.1665795894e-2f;
  y = y * x + 1.6666665459e-1f;
  y = y * x + 5.0000001201e-1f;
  y = y * z + x;
  y = y + 1.0f;
  int n = (int)fx;
  y = y * __uint_as_float((uint32_t)(n + 127) << 23);
  return y;
}

// XLA GenerateVF32Log replica = Pommier/Eigen3.3 log_ps (Horner + tail:
// y+=e*q1; y-=0.5*z; x+=y; x+=e*q2). NO contraction.
__device__ static float xla_log(float x_in) {
#pragma clang fp contract(off)
  float xv = fmaxf(x_in, 1.17549435e-38f);      // min_norm_pos clamp
  uint32_t bits = __float_as_uint(xv);
  float e = (float)((int)(bits >> 23) - 126);
  float x = __uint_as_float((bits & 0x007FFFFFu) | 0x3F000000u);  // [0.5,1)
  bool m = (x < 0.707106781186547524f);
  float tmp = m ? x : 0.0f;
  x = x - 1.0f;
  e = e - (m ? 1.0f : 0.0f);
  x = x + tmp;
  float z = x * x;
  float y = 7.0376836292e-2f;
  y = y * x + -1.1514610310e-1f;
  y = y * x + 1.1676998740e-1f;
  y = y * x + -1.2420140846e-1f;
  y = y * x + 1.4249322787e-1f;
  y = y * x + -1.6668057665e-1f;
  y = y * x + 2.0000714765e-1f;
  y = y * x + -2.4999993993e-1f;
  y = y * x + 3.3333331174e-1f;
  y = y * x;
  y = y * z;
  float t1 = e * -2.12194440e-4f;
  y = y + t1;
  float t2 = z * 0.5f;
  y = y - t2;
  x = x + y;
  float t3 = e * 0.693359375f;
  x = x + t3;
  return x;
}

// ---------------- kernels ----------------

__global__ void k_sentinel(float* out, float d) {
  out[0] = d;
}

// v0 one-hot (B,C,V) -> idx (B,V) u8
__global__ __launch_bounds__(256) void k_idx(const float* __restrict__ v0,
                                             uint8_t* __restrict__ idx) {
  int t = blockIdx.x * 256 + threadIdx.x;          // b*V + v
  int b = t >> 9, v = t & 511;
  const float* p = v0 + (size_t)b * (C_DIM * V_DIM) + v;
  int cf = 0;
#pragma unroll
  for (int c = 0; c < C_DIM; ++c)
    if (p[c * V_DIM] > 0.5f) cf = c;
  idx[t] = (uint8_t)cf;
}

// W (c,h,v) -> Wt (c,v,h)
__global__ __launch_bounds__(256) void k_wt(const float* __restrict__ W,
                                            float* __restrict__ Wt) {
  int t = blockIdx.x * 256 + threadIdx.x;          // (c, v, h)
  int h = t & 255; int rest = t >> 8; int v = rest & 511; int c = rest >> 9;
  Wt[t] = W[((size_t)c * H_DIM + h) * V_DIM + v];
}

// h = bernoulli(sigmoid(kc-slab-folded k-ascending sum + c1))
// In-LDS compaction (round 7): soff[512] = selected k offsets asc,
// jb[s] = kc-panel boundaries. Order bit-identical to round 6.
__global__ __launch_bounds__(256) void k_sample_h(
    const float* __restrict__ Wt, const float* __restrict__ c1,
    const uint8_t* __restrict__ idx,
    float* __restrict__ out_h, uint32_t* __restrict__ out_mask,
    uint32_t key0, uint32_t key1) {
  __shared__ uint8_t  sidx[V_DIM];
  __shared__ uint32_t soff[V_DIM];     // (c*512+v)*1024 byte offsets, k asc
  __shared__ uint16_t cnt[8][5];       // per 64-lane segment, per class
  __shared__ uint16_t base[8][5];      // global start position
  __shared__ uint16_t jb[10];          // panel boundaries in j-space
  int b = blockIdx.x;
  int t = threadIdx.x;
  if (t < 128)
    ((uint32_t*)sidx)[t] = ((const uint32_t*)(idx + (size_t)b * V_DIM))[t];
  __syncthreads();

  int lane = t & 63, wv = t >> 6;
  int v0 = t,       c0 = sidx[v0];
  int v1 = t + 256, c1i = sidx[v1];
  int rank0, rank1;
  {
    unsigned long long bal[5];
#pragma unroll
    for (int cc = 0; cc < 5; ++cc) bal[cc] = __ballot(c0 == cc);
    if (lane == 0) {
#pragma unroll
      for (int cc = 0; cc < 5; ++cc) cnt[wv][cc] = (uint16_t)__popcll(bal[cc]);
    }
    rank0 = (int)__popcll(bal[c0] & ((1ull << lane) - 1ull));
  }
  {
    unsigned long long bal[5];
#pragma unroll
    for (int cc = 0; cc < 5; ++cc) bal[cc] = __ballot(c1i == cc);
    if (lane == 0) {
#pragma unroll
      for (int cc = 0; cc < 5; ++cc) cnt[4 + wv][cc] = (uint16_t)__popcll(bal[cc]);
    }
    rank1 = (int)__popcll(bal[c1i] & ((1ull << lane) - 1ull));
  }
  __syncthreads();
  if (t == 0) {
    int pos = 0;
    for (int cc = 0; cc < 5; ++cc)
      for (int g = 0; g < 8; ++g) { base[g][cc] = (uint16_t)pos; pos += cnt[g][cc]; }
  }
  __syncthreads();
  soff[base[wv][c0] + rank0]       = (uint32_t)(c0 * V_DIM + v0) << 10;   // k*1024B
  soff[base[4 + wv][c1i] + rank1]  = (uint32_t)(c1i * V_DIM + v1) << 10;
  __syncthreads();
  if (t < 10) {
    uint32_t target = (uint32_t)(t * KC) << 10;
    int lo = 0, hi = V_DIM;
    while (lo < hi) { int mid = (lo + hi) >> 1;
      if (soff[mid] < target) lo = mid + 1; else hi = mid; }
    jb[t] = (uint16_t)lo;
  }
  __syncthreads();

  // main accumulation: h = t
  const char* Wh = (const char*)Wt + (size_t)t * 4;
  float total = 0.0f;
  for (int s = 0; s < 9; ++s) {
    int j = jb[s], jend = jb[s + 1];
    float psum = 0.0f;
    for (; j + 4 <= jend; j += 4) {
      float w0 = *(const float*)(Wh + soff[j]);
      float w1 = *(const float*)(Wh + soff[j + 1]);
      float w2 = *(const float*)(Wh + soff[j + 2]);
      float w3 = *(const float*)(Wh + soff[j + 3]);
      psum += w0; psum += w1; psum += w2; psum += w3;
    }
    for (; j < jend; ++j) psum += *(const float*)(Wh + soff[j]);
    total += psum;
  }

  float tt = total + c1[t];
  float p = 1.0f / (1.0f + xla_exp(-tt));   // IEEE div, logistic exp form

  uint32_t i = (uint32_t)(b * H_DIM + t);
  float u = bits_to_unit_float(rng_bits(key0, key1, i));
  bool hb = (u < p);
  if (out_h) out_h[(size_t)b * H_DIM + t] = hb ? 1.0f : 0.0f;

  unsigned long long m = __ballot(hb);
  if ((t & 63) == 0) {
    out_mask[(size_t)b * 8 + wv * 2 + 0] = (uint32_t)(m & 0xFFFFFFFFull);
    out_mask[(size_t)b * 8 + wv * 2 + 1] = (uint32_t)(m >> 32);
  }
}

// v = categorical over c of (sum_{set h asc} W[c,h,v] + b2 + gumbel).
// Per-b ballot compaction of set h-bits -> LDS byte-offset list; sum
// is h-ascending over set bits = sequential h with exact zero-skip.
// 2 b-groups x 256 threads per block; float2 v-pair per thread.
__global__ __launch_bounds__(512) void k_sample_v(
    const float* __restrict__ W, const float* __restrict__ b2,
    const uint32_t* __restrict__ mask, uint8_t* __restrict__ idx_out,
    uint32_t key0, uint32_t key1) {
  __shared__ uint32_t hoff[2][H_DIM];   // h*2048 byte offsets, set-h asc
  __shared__ uint16_t scnt[2][4];       // per-wave set counts
  __shared__ uint16_t nsel[2];
  int tid = threadIdx.x;
  int grp = tid >> 8;                   // 0/1
  int tl  = tid & 255;                  // local thread = h index
  int b   = blockIdx.x * 2 + grp;

  uint32_t mword = mask[(size_t)b * 8 + (tl >> 5)];
  bool bit = ((mword >> (tl & 31)) & 1u) != 0u;
  unsigned long long bal = __ballot(bit);
  int lane = tid & 63;
  int wv_loc = tl >> 6;                 // 0..3 within group
  if (lane == 0) scnt[grp][wv_loc] = (uint16_t)__popcll(bal);
  __syncthreads();
  int bse = 0;
#pragma unroll
  for (int w = 0; w < 4; ++w) if (w < wv_loc) bse += scnt[grp][w];
  int rank = (int)__popcll(bal & ((1ull << lane) - 1ull));
  if (bit) hoff[grp][bse + rank] = (uint32_t)tl << 11;   // h*2048
  if (tl == 0)
    nsel[grp] = (uint16_t)(scnt[grp][0] + scnt[grp][1] +
                           scnt[grp][2] + scnt[grp][3]);
  __syncthreads();
  int n = nsel[grp];

  // accumulate: thread covers v-pair (2*tl, 2*tl+1)
  const char* Wv = (const char*)W + (size_t)tl * 8;
  float acc[C_DIM][2];
#pragma unroll
  for (int c = 0; c < C_DIM; ++c) {
    const char* Wc = Wv + (size_t)c * (H_DIM * V_DIM * 4);
    float a0 = 0.0f, a1 = 0.0f;
    int j = 0;
    for (; j + 4 <= n; j += 4) {
      uint32_t o0 = hoff[grp][j],     o1 = hoff[grp][j + 1];
      uint32_t o2 = hoff[grp][j + 2], o3 = hoff[grp][j + 3];
      float2 w0 = *(const float2*)(Wc + o0);
      float2 w1 = *(const float2*)(Wc + o1);
      float2 w2 = *(const float2*)(Wc + o2);
      float2 w3 = *(const float2*)(Wc + o3);
      a0 += w0.x; a1 += w0.y;
      a0 += w1.x; a1 += w1.y;
      a0 += w2.x; a1 += w2.y;
      a0 += w3.x; a1 += w3.y;
    }
    for (; j < n; ++j) {
      float2 w = *(const float2*)(Wc + hoff[grp][j]);
      a0 += w.x; a1 += w.y;
    }
    acc[c][0] = a0; acc[c][1] = a1;
  }

  // epilogue: gumbel + first-max argmax over c (ascending), 2 v's
  int v0 = tl * 2;
  float best0 = 0.0f, best1 = 0.0f;
  int bc0 = 0, bc1 = 0;
#pragma unroll
  for (int c = 0; c < C_DIM; ++c) {
    float bias0 = b2[c * V_DIM + v0];
    float bias1 = b2[c * V_DIM + v0 + 1];
    uint32_t i0 = (uint32_t)(((uint32_t)b * C_DIM + c) * V_DIM + v0);
    float uf0 = bits_to_unit_float(rng_bits(key0, key1, i0));
    if (uf0 == 0.0f) uf0 = 1.17549435e-38f;          // u + tiny semantics
    float g0 = -xla_log(-xla_log(uf0));
    float z0 = g0 + (acc[c][0] + bias0);
    float uf1 = bits_to_unit_float(rng_bits(key0, key1, i0 + 1));
    if (uf1 == 0.0f) uf1 = 1.17549435e-38f;
    float g1 = -xla_log(-xla_log(uf1));
    float z1 = g1 + (acc[c][1] + bias1);
    if (c == 0 || z0 > best0) { best0 = z0; bc0 = c; }
    if (c == 0 || z1 > best1) { best1 = z1; bc1 = c; }
  }
  uint16_t pack = (uint16_t)((uint16_t)bc0 | ((uint16_t)bc1 << 8));
  *(uint16_t*)(idx_out + (size_t)b * V_DIM + v0) = pack;
}

// idx -> one-hot f32 (B,C,V)
__global__ __launch_bounds__(256) void k_onehot(const uint8_t* __restrict__ idx,
                                                float* __restrict__ out) {
  int t = blockIdx.x * 256 + threadIdx.x;     // b*C*V + c*V + v
  int v = t & 511; int rest = t >> 9; int c = rest % C_DIM; int b = rest / C_DIM;
  out[t] = (idx[(size_t)b * V_DIM + v] == c) ? 1.0f : 0.0f;
}

// ---------------- launch ----------------

extern "C" void kernel_launch(void* const* d_in, const int* in_sizes, int n_in,
                              void* d_out, int out_size, void* d_ws, size_t ws_size,
                              hipStream_t stream) {
  float* out = (float*)d_out;

  // ---- structural sentinels (verified silent in rounds 5-7) ----
  const size_t WS_NEED = 2621440ull + 8388608ull + 524288ull;  // 11,534,336 B
  float D = 0.0f;
  if (n_in < 4)                       D = 910.0f + (float)n_in;
  else if (in_sizes[0] != 41943040)   D = 920.0f;
  else if (in_sizes[1] != 655360)     D = 921.0f;
  else if (in_sizes[2] != 2560)       D = 922.0f;
  else if (in_sizes[3] != 256)        D = 923.0f;
  else if (out_size != 50331648)      D = 930.0f + (float)out_size * 1e-6f;
  else if (ws_size < WS_NEED)         D = 100.0f + (float)(ws_size >> 20);
  if (D != 0.0f) {
    hipLaunchKernelGGL(k_sentinel, dim3(1), dim3(1), 0, stream, out, D);
    return;
  }

  const float* v0 = (const float*)d_in[0];
  const float* W  = (const float*)d_in[1];
  const float* b2 = (const float*)d_in[2];   // (C,V)
  const float* c1 = (const float*)d_in[3];   // (H)

  float* out_v  = out;                                         // B*C*V
  float* out_h  = out + (size_t)B_DIM * C_DIM * V_DIM;         // B*H (final h)
  float* out_h0 = out_h + (size_t)B_DIM * H_DIM;               // B*H (h|v0)

  char* ws = (char*)d_ws;
  float*    Wt   = (float*)(ws);                    // 2,621,440 B
  uint8_t*  idx  = (uint8_t*)(ws + 2621440);        // 8,388,608 B
  uint32_t* mask = (uint32_t*)(ws + 11010048);      //   524,288 B

  // partitionable (fold-like) split of key(42) into 5 subkeys
  uint32_t keys[5][2];
  for (int i = 0; i < 5; ++i) {
    TFOut r = tf2x32(0u, 42u, 0u, (uint32_t)i);
    keys[i][0] = r.a; keys[i][1] = r.b;
  }

  hipLaunchKernelGGL(k_wt,  dim3(2560),  dim3(256), 0, stream, W, Wt);
  hipLaunchKernelGGL(k_idx, dim3(32768), dim3(256), 0, stream, v0, idx);

  // h0 = sample_h(keys[0], v0) -> h_given_v0 output + mask
  hipLaunchKernelGGL(k_sample_h, dim3(B_DIM), dim3(256), 0, stream,
                     Wt, c1, idx, out_h0, mask, keys[0][0], keys[0][1]);
  // iter 0: v = sample_v(keys[1], h0); h1 = sample_h(keys[2], v)
  hipLaunchKernelGGL(k_sample_v, dim3(B_DIM / 2), dim3(512), 0, stream,
                     W, b2, mask, idx, keys[1][0], keys[1][1]);
  hipLaunchKernelGGL(k_sample_h, dim3(B_DIM), dim3(256), 0, stream,
                     Wt, c1, idx, (float*)nullptr, mask, keys[2][0], keys[2][1]);
  // iter 1: v = sample_v(keys[3], h1); h2 = sample_h(keys[4], v)
  hipLaunchKernelGGL(k_sample_v, dim3(B_DIM / 2), dim3(512), 0, stream,
                     W, b2, mask, idx, keys[3][0], keys[3][1]);
  hipLaunchKernelGGL(k_sample_h, dim3(B_DIM), dim3(256), 0, stream,
                     Wt, c1, idx, out_h, mask, keys[4][0], keys[4][1]);
  // final v one-hot output
  hipLaunchKernelGGL(k_onehot, dim3(163840), dim3(256), 0, stream, idx, out_v);
}

// Round 10
// 3514.197 us; speedup vs baseline: 1.0020x; 1.0020x over previous
//
#include <hip/hip_runtime.h>
#include <cstdint>
#include <cstddef>

// =====================================================================
// RBM Gibbs sampling, bit-exact replication of JAX-on-CPU reference.
// ROUND 9 (perf): k_sample_v inner loop restructured for MLP — the 5
// c-streams are interleaved into the j-loop (10 independent float2
// loads in flight per j-pair, saddr-form via readfirstlane-uniform
// offsets) feeding 10 independent accumulator chains. Per-chain add
// order unchanged (h-ascending) => bit-identical. Round-8 analysis:
// VALU fix worked (54->32%) but dur rose — kernel is L2-latency-bound
// (~2x the 610us/dispatch L2-BW floor with only 4 loads in flight).
// Semantics FROZEN (rounds 6-8 passed, absmax=0):
//  - threefry2x32 partitionable; fold-like split; seed(42)->(0,42).
//  - cephes-Horner exp, Pommier-Horner log (q1/q2 tail), no contract.
//  - sigmoid = 1/(1+exp(-x)) IEEE div; gumbel tiny-clamp; first-max
//    argmax; bernoulli u<p; v-GEMM K=256 single sequential chain.
//  - h-GEMM: Eigen gebp kc=320 slab fold, k ascending (c-major).
// =====================================================================

#define B_DIM 16384
#define C_DIM 5
#define H_DIM 256
#define V_DIM 512
#define KC    320   // Eigen MT gebp kc (Zen5 48KB L1d: min(435,320)=320)

struct TFOut { uint32_t a, b; };

__host__ __device__ static inline TFOut tf2x32(uint32_t k0, uint32_t k1,
                                               uint32_t c0, uint32_t c1) {
  uint32_t ks2 = k0 ^ k1 ^ 0x1BD11BDAu;
  uint32_t x0 = c0 + k0, x1 = c1 + k1;
#define TF_R(r) { x0 += x1; x1 = (x1 << r) | (x1 >> (32 - r)); x1 ^= x0; }
  TF_R(13) TF_R(15) TF_R(26) TF_R(6)
  x0 += k1;  x1 += ks2 + 1u;
  TF_R(17) TF_R(29) TF_R(16) TF_R(24)
  x0 += ks2; x1 += k0 + 2u;
  TF_R(13) TF_R(15) TF_R(26) TF_R(6)
  x0 += k0;  x1 += k1 + 3u;
  TF_R(17) TF_R(29) TF_R(16) TF_R(24)
  x0 += k1;  x1 += ks2 + 4u;
  TF_R(13) TF_R(15) TF_R(26) TF_R(6)
  x0 += ks2; x1 += k0 + 5u;
#undef TF_R
  TFOut o; o.a = x0; o.b = x1; return o;
}

// partitionable random_bits, 32-bit width, element index i (< 2^32)
__device__ static inline uint32_t rng_bits(uint32_t k0, uint32_t k1, uint32_t i) {
  TFOut r = tf2x32(k0, k1, 0u, i);
  return r.a ^ r.b;
}

__device__ static inline float bits_to_unit_float(uint32_t bits) {
  return __uint_as_float((bits >> 9) | 0x3F800000u) - 1.0f;
}

// XLA GenerateVF32Exp replica (cephes Horner port), mul+add separate,
// NO contraction.
__device__ static float xla_exp(float x_in) {
#pragma clang fp contract(off)
  float x = fminf(x_in, 88.3762626647950f);
  x = fmaxf(x, -88.3762626647949f);
  float fx = floorf(x * 1.44269504088896341f + 0.5f);
  float tmp = fx * 0.693359375f;
  float z = fx * -2.12194440e-4f;
  x = x - tmp;
  x = x - z;
  z = x * x;
  float y = 1.9875691500e-4f;
  y = y * x + 1.3981999507e-3f;
  y = y * x + 8.3334519073e-3f;
  y = y * x + 4.1665795894e-2f;
  y = y * x + 1.6666665459e-1f;
  y = y * x + 5.0000001201e-1f;
  y = y * z + x;
  y = y + 1.0f;
  int n = (int)fx;
  y = y * __uint_as_float((uint32_t)(n + 127) << 23);
  return y;
}

// XLA GenerateVF32Log replica = Pommier/Eigen3.3 log_ps (Horner + tail:
// y+=e*q1; y-=0.5*z; x+=y; x+=e*q2). NO contraction.
__device__ static float xla_log(float x_in) {
#pragma clang fp contract(off)
  float xv = fmaxf(x_in, 1.17549435e-38f);      // min_norm_pos clamp
  uint32_t bits = __float_as_uint(xv);
  float e = (float)((int)(bits >> 23) - 126);
  float x = __uint_as_float((bits & 0x007FFFFFu) | 0x3F000000u);  // [0.5,1)
  bool m = (x < 0.707106781186547524f);
  float tmp = m ? x : 0.0f;
  x = x - 1.0f;
  e = e - (m ? 1.0f : 0.0f);
  x = x + tmp;
  float z = x * x;
  float y = 7.0376836292e-2f;
  y = y * x + -1.1514610310e-1f;
  y = y * x + 1.1676998740e-1f;
  y = y * x + -1.2420140846e-1f;
  y = y * x + 1.4249322787e-1f;
  y = y * x + -1.6668057665e-1f;
  y = y * x + 2.0000714765e-1f;
  y = y * x + -2.4999993993e-1f;
  y = y * x + 3.3333331174e-1f;
  y = y * x;
  y = y * z;
  float t1 = e * -2.12194440e-4f;
  y = y + t1;
  float t2 = z * 0.5f;
  y = y - t2;
  x = x + y;
  float t3 = e * 0.693359375f;
  x = x + t3;
  return x;
}

// ---------------- kernels ----------------

__global__ void k_sentinel(float* out, float d) {
  out[0] = d;
}

// v0 one-hot (B,C,V) -> idx (B,V) u8
__global__ __launch_bounds__(256) void k_idx(const float* __restrict__ v0,
                                             uint8_t* __restrict__ idx) {
  int t = blockIdx.x * 256 + threadIdx.x;          // b*V + v
  int b = t >> 9, v = t & 511;
  const float* p = v0 + (size_t)b * (C_DIM * V_DIM) + v;
  int cf = 0;
#pragma unroll
  for (int c = 0; c < C_DIM; ++c)
    if (p[c * V_DIM] > 0.5f) cf = c;
  idx[t] = (uint8_t)cf;
}

// W (c,h,v) -> Wt (c,v,h)
__global__ __launch_bounds__(256) void k_wt(const float* __restrict__ W,
                                            float* __restrict__ Wt) {
  int t = blockIdx.x * 256 + threadIdx.x;          // (c, v, h)
  int h = t & 255; int rest = t >> 8; int v = rest & 511; int c = rest >> 9;
  Wt[t] = W[((size_t)c * H_DIM + h) * V_DIM + v];
}

// h = bernoulli(sigmoid(kc-slab-folded k-ascending sum + c1))
// In-LDS compaction (round 7): soff[512] = selected k offsets asc,
// jb[s] = kc-panel boundaries. Order bit-identical to round 6.
__global__ __launch_bounds__(256) void k_sample_h(
    const float* __restrict__ Wt, const float* __restrict__ c1,
    const uint8_t* __restrict__ idx,
    float* __restrict__ out_h, uint32_t* __restrict__ out_mask,
    uint32_t key0, uint32_t key1) {
  __shared__ uint8_t  sidx[V_DIM];
  __shared__ uint32_t soff[V_DIM];     // (c*512+v)*1024 byte offsets, k asc
  __shared__ uint16_t cnt[8][5];       // per 64-lane segment, per class
  __shared__ uint16_t base[8][5];      // global start position
  __shared__ uint16_t jb[10];          // panel boundaries in j-space
  int b = blockIdx.x;
  int t = threadIdx.x;
  if (t < 128)
    ((uint32_t*)sidx)[t] = ((const uint32_t*)(idx + (size_t)b * V_DIM))[t];
  __syncthreads();

  int lane = t & 63, wv = t >> 6;
  int v0 = t,       c0 = sidx[v0];
  int v1 = t + 256, c1i = sidx[v1];
  int rank0, rank1;
  {
    unsigned long long bal[5];
#pragma unroll
    for (int cc = 0; cc < 5; ++cc) bal[cc] = __ballot(c0 == cc);
    if (lane == 0) {
#pragma unroll
      for (int cc = 0; cc < 5; ++cc) cnt[wv][cc] = (uint16_t)__popcll(bal[cc]);
    }
    rank0 = (int)__popcll(bal[c0] & ((1ull << lane) - 1ull));
  }
  {
    unsigned long long bal[5];
#pragma unroll
    for (int cc = 0; cc < 5; ++cc) bal[cc] = __ballot(c1i == cc);
    if (lane == 0) {
#pragma unroll
      for (int cc = 0; cc < 5; ++cc) cnt[4 + wv][cc] = (uint16_t)__popcll(bal[cc]);
    }
    rank1 = (int)__popcll(bal[c1i] & ((1ull << lane) - 1ull));
  }
  __syncthreads();
  if (t == 0) {
    int pos = 0;
    for (int cc = 0; cc < 5; ++cc)
      for (int g = 0; g < 8; ++g) { base[g][cc] = (uint16_t)pos; pos += cnt[g][cc]; }
  }
  __syncthreads();
  soff[base[wv][c0] + rank0]       = (uint32_t)(c0 * V_DIM + v0) << 10;   // k*1024B
  soff[base[4 + wv][c1i] + rank1]  = (uint32_t)(c1i * V_DIM + v1) << 10;
  __syncthreads();
  if (t < 10) {
    uint32_t target = (uint32_t)(t * KC) << 10;
    int lo = 0, hi = V_DIM;
    while (lo < hi) { int mid = (lo + hi) >> 1;
      if (soff[mid] < target) lo = mid + 1; else hi = mid; }
    jb[t] = (uint16_t)lo;
  }
  __syncthreads();

  // main accumulation: h = t
  const char* Wh = (const char*)Wt + (size_t)t * 4;
  float total = 0.0f;
  for (int s = 0; s < 9; ++s) {
    int j = jb[s], jend = jb[s + 1];
    float psum = 0.0f;
    for (; j + 4 <= jend; j += 4) {
      float w0 = *(const float*)(Wh + soff[j]);
      float w1 = *(const float*)(Wh + soff[j + 1]);
      float w2 = *(const float*)(Wh + soff[j + 2]);
      float w3 = *(const float*)(Wh + soff[j + 3]);
      psum += w0; psum += w1; psum += w2; psum += w3;
    }
    for (; j < jend; ++j) psum += *(const float*)(Wh + soff[j]);
    total += psum;
  }

  float tt = total + c1[t];
  float p = 1.0f / (1.0f + xla_exp(-tt));   // IEEE div, logistic exp form

  uint32_t i = (uint32_t)(b * H_DIM + t);
  float u = bits_to_unit_float(rng_bits(key0, key1, i));
  bool hb = (u < p);
  if (out_h) out_h[(size_t)b * H_DIM + t] = hb ? 1.0f : 0.0f;

  unsigned long long m = __ballot(hb);
  if ((t & 63) == 0) {
    out_mask[(size_t)b * 8 + wv * 2 + 0] = (uint32_t)(m & 0xFFFFFFFFull);
    out_mask[(size_t)b * 8 + wv * 2 + 1] = (uint32_t)(m >> 32);
  }
}

// v = categorical over c of (sum_{set h asc} W[c,h,v] + b2 + gumbel).
// Per-b ballot compaction of set h-bits -> LDS byte-offset list; sum
// is h-ascending over set bits = sequential h with exact zero-skip.
// 2 b-groups x 256 threads per block; float2 v-pair per thread.
// Inner loop: c-interleaved, 10 loads in flight per j-pair (MLP).
__global__ __launch_bounds__(512) void k_sample_v(
    const float* __restrict__ W, const float* __restrict__ b2,
    const uint32_t* __restrict__ mask, uint8_t* __restrict__ idx_out,
    uint32_t key0, uint32_t key1) {
  __shared__ uint32_t hoff[2][H_DIM];   // h*2048 byte offsets, set-h asc
  __shared__ uint16_t scnt[2][4];       // per-wave set counts
  __shared__ uint16_t nsel[2];
  int tid = threadIdx.x;
  int grp = tid >> 8;                   // 0/1
  int tl  = tid & 255;                  // local thread = h index
  int b   = blockIdx.x * 2 + grp;

  uint32_t mword = mask[(size_t)b * 8 + (tl >> 5)];
  bool bit = ((mword >> (tl & 31)) & 1u) != 0u;
  unsigned long long bal = __ballot(bit);
  int lane = tid & 63;
  int wv_loc = tl >> 6;                 // 0..3 within group
  if (lane == 0) scnt[grp][wv_loc] = (uint16_t)__popcll(bal);
  __syncthreads();
  int bse = 0;
#pragma unroll
  for (int w = 0; w < 4; ++w) if (w < wv_loc) bse += scnt[grp][w];
  int rank = (int)__popcll(bal & ((1ull << lane) - 1ull));
  if (bit) hoff[grp][bse + rank] = (uint32_t)tl << 11;   // h*2048
  if (tl == 0)
    nsel[grp] = (uint16_t)(scnt[grp][0] + scnt[grp][1] +
                           scnt[grp][2] + scnt[grp][3]);
  __syncthreads();
  int n = nsel[grp];

  // accumulate: thread covers v-pair (2*tl, 2*tl+1); 10 chains (5c x 2v)
  const char* Wv = (const char*)W + (size_t)tl * 8;
  const size_t CS = (size_t)H_DIM * V_DIM * 4;      // 512 KB c-stride
  float a0[C_DIM], a1[C_DIM];
#pragma unroll
  for (int c = 0; c < C_DIM; ++c) { a0[c] = 0.0f; a1[c] = 0.0f; }
  int j = 0;
  for (; j + 2 <= n; j += 2) {
    uint32_t oa = (uint32_t)__builtin_amdgcn_readfirstlane((int)hoff[grp][j]);
    uint32_t ob = (uint32_t)__builtin_amdgcn_readfirstlane((int)hoff[grp][j + 1]);
    float2 wa[C_DIM], wb[C_DIM];
#pragma unroll
    for (int c = 0; c < C_DIM; ++c) {
      wa[c] = *(const float2*)(Wv + (size_t)c * CS + oa);
      wb[c] = *(const float2*)(Wv + (size_t)c * CS + ob);
    }
#pragma unroll
    for (int c = 0; c < C_DIM; ++c) {
      a0[c] += wa[c].x; a1[c] += wa[c].y;      // h = oa (earlier)
      a0[c] += wb[c].x; a1[c] += wb[c].y;      // h = ob (later)
    }
  }
  if (j < n) {
    uint32_t oa = (uint32_t)__builtin_amdgcn_readfirstlane((int)hoff[grp][j]);
#pragma unroll
    for (int c = 0; c < C_DIM; ++c) {
      float2 wa = *(const float2*)(Wv + (size_t)c * CS + oa);
      a0[c] += wa.x; a1[c] += wa.y;
    }
  }

  // epilogue: gumbel + first-max argmax over c (ascending), 2 v's
  int v0 = tl * 2;
  float best0 = 0.0f, best1 = 0.0f;
  int bc0 = 0, bc1 = 0;
#pragma unroll
  for (int c = 0; c < C_DIM; ++c) {
    float bias0 = b2[c * V_DIM + v0];
    float bias1 = b2[c * V_DIM + v0 + 1];
    uint32_t i0 = (uint32_t)(((uint32_t)b * C_DIM + c) * V_DIM + v0);
    float uf0 = bits_to_unit_float(rng_bits(key0, key1, i0));
    if (uf0 == 0.0f) uf0 = 1.17549435e-38f;          // u + tiny semantics
    float g0 = -xla_log(-xla_log(uf0));
    float z0 = g0 + (a0[c] + bias0);
    float uf1 = bits_to_unit_float(rng_bits(key0, key1, i0 + 1));
    if (uf1 == 0.0f) uf1 = 1.17549435e-38f;
    float g1 = -xla_log(-xla_log(uf1));
    float z1 = g1 + (a1[c] + bias1);
    if (c == 0 || z0 > best0) { best0 = z0; bc0 = c; }
    if (c == 0 || z1 > best1) { best1 = z1; bc1 = c; }
  }
  uint16_t pack = (uint16_t)((uint16_t)bc0 | ((uint16_t)bc1 << 8));
  *(uint16_t*)(idx_out + (size_t)b * V_DIM + v0) = pack;
}

// idx -> one-hot f32 (B,C,V)
__global__ __launch_bounds__(256) void k_onehot(const uint8_t* __restrict__ idx,
                                                float* __restrict__ out) {
  int t = blockIdx.x * 256 + threadIdx.x;     // b*C*V + c*V + v
  int v = t & 511; int rest = t >> 9; int c = rest % C_DIM; int b = rest / C_DIM;
  out[t] = (idx[(size_t)b * V_DIM + v] == c) ? 1.0f : 0.0f;
}

// ---------------- launch ----------------

extern "C" void kernel_launch(void* const* d_in, const int* in_sizes, int n_in,
                              void* d_out, int out_size, void* d_ws, size_t ws_size,
                              hipStream_t stream) {
  float* out = (float*)d_out;

  // ---- structural sentinels (verified silent in rounds 5-8) ----
  const size_t WS_NEED = 2621440ull + 8388608ull + 524288ull;  // 11,534,336 B
  float D = 0.0f;
  if (n_in < 4)                       D = 910.0f + (float)n_in;
  else if (in_sizes[0] != 41943040)   D = 920.0f;
  else if (in_sizes[1] != 655360)     D = 921.0f;
  else if (in_sizes[2] != 2560)       D = 922.0f;
  else if (in_sizes[3] != 256)        D = 923.0f;
  else if (out_size != 50331648)      D = 930.0f + (float)out_size * 1e-6f;
  else if (ws_size < WS_NEED)         D = 100.0f + (float)(ws_size >> 20);
  if (D != 0.0f) {
    hipLaunchKernelGGL(k_sentinel, dim3(1), dim3(1), 0, stream, out, D);
    return;
  }

  const float* v0 = (const float*)d_in[0];
  const float* W  = (const float*)d_in[1];
  const float* b2 = (const float*)d_in[2];   // (C,V)
  const float* c1 = (const float*)d_in[3];   // (H)

  float* out_v  = out;                                         // B*C*V
  float* out_h  = out + (size_t)B_DIM * C_DIM * V_DIM;         // B*H (final h)
  float* out_h0 = out_h + (size_t)B_DIM * H_DIM;               // B*H (h|v0)

  char* ws = (char*)d_ws;
  float*    Wt   = (float*)(ws);                    // 2,621,440 B
  uint8_t*  idx  = (uint8_t*)(ws + 2621440);        // 8,388,608 B
  uint32_t* mask = (uint32_t*)(ws + 11010048);      //   524,288 B

  // partitionable (fold-like) split of key(42) into 5 subkeys
  uint32_t keys[5][2];
  for (int i = 0; i < 5; ++i) {
    TFOut r = tf2x32(0u, 42u, 0u, (uint32_t)i);
    keys[i][0] = r.a; keys[i][1] = r.b;
  }

  hipLaunchKernelGGL(k_wt,  dim3(2560),  dim3(256), 0, stream, W, Wt);
  hipLaunchKernelGGL(k_idx, dim3(32768), dim3(256), 0, stream, v0, idx);

  // h0 = sample_h(keys[0], v0) -> h_given_v0 output + mask
  hipLaunchKernelGGL(k_sample_h, dim3(B_DIM), dim3(256), 0, stream,
                     Wt, c1, idx, out_h0, mask, keys[0][0], keys[0][1]);
  // iter 0: v = sample_v(keys[1], h0); h1 = sample_h(keys[2], v)
  hipLaunchKernelGGL(k_sample_v, dim3(B_DIM / 2), dim3(512), 0, stream,
                     W, b2, mask, idx, keys[1][0], keys[1][1]);
  hipLaunchKernelGGL(k_sample_h, dim3(B_DIM), dim3(256), 0, stream,
                     Wt, c1, idx, (float*)nullptr, mask, keys[2][0], keys[2][1]);
  // iter 1: v = sample_v(keys[3], h1); h2 = sample_h(keys[4], v)
  hipLaunchKernelGGL(k_sample_v, dim3(B_DIM / 2), dim3(512), 0, stream,
                     W, b2, mask, idx, keys[3][0], keys[3][1]);
  hipLaunchKernelGGL(k_sample_h, dim3(B_DIM), dim3(256), 0, stream,
                     Wt, c1, idx, out_h, mask, keys[4][0], keys[4][1]);
  // final v one-hot output
  hipLaunchKernelGGL(k_onehot, dim3(163840), dim3(256), 0, stream, idx, out_v);
}

// Round 11
// 2763.427 us; speedup vs baseline: 1.2742x; 1.2717x over previous
//
#include <hip/hip_runtime.h>
#include <cstdint>
#include <cstddef>

// =====================================================================
// RBM Gibbs sampling, bit-exact replication of JAX-on-CPU reference.
// ROUND 10 (perf): k_sample_v traffic reduction. R8-R10 all plateaued
// at ~1250us with identical L2 traffic (21 GB/dispatch = 16.4 TB/s
// effective) despite very different VALU/occupancy => L2-BW ceiling.
// New scheme: BT=128 b's per 1024-thread block over a contiguous
// 32-v tile (new Wv[vt][c][h][32] layout via k_wv pre-pass; per-(c,vt)
// tile = 32 KB = exactly L1, sequential lines). Per-b h-lists (uint8,
// LDS stride 260) + per-c __syncthreads keep the tile L1-resident:
// L2 traffic drops 8x to 2.6 GB; floor becomes L1 BW (~280us).
// Add order per (b,c,v) unchanged: h-ascending over set bits, exact
// skips => bit-identical.
// Semantics FROZEN (rounds 6-10 passed, absmax=0):
//  - threefry2x32 partitionable; fold-like split; seed(42)->(0,42).
//  - cephes-Horner exp, Pommier-Horner log (q1/q2 tail), no contract.
//  - sigmoid = 1/(1+exp(-x)) IEEE div; gumbel tiny-clamp; first-max
//    argmax; bernoulli u<p; v-GEMM K=256 single sequential chain.
//  - h-GEMM: Eigen gebp kc=320 slab fold, k ascending (c-major).
// ws grows to 13.5 MB (Wt+Wv+idx+mask); sentinel reads back ws_size
// as absmax=100+MB if short.
// =====================================================================

#define B_DIM 16384
#define C_DIM 5
#define H_DIM 256
#define V_DIM 512
#define KC    320   // Eigen MT gebp kc (Zen5 48KB L1d: min(435,320)=320)
#define BT    128   // b's per k_sample_v block

struct TFOut { uint32_t a, b; };

__host__ __device__ static inline TFOut tf2x32(uint32_t k0, uint32_t k1,
                                               uint32_t c0, uint32_t c1) {
  uint32_t ks2 = k0 ^ k1 ^ 0x1BD11BDAu;
  uint32_t x0 = c0 + k0, x1 = c1 + k1;
#define TF_R(r) { x0 += x1; x1 = (x1 << r) | (x1 >> (32 - r)); x1 ^= x0; }
  TF_R(13) TF_R(15) TF_R(26) TF_R(6)
  x0 += k1;  x1 += ks2 + 1u;
  TF_R(17) TF_R(29) TF_R(16) TF_R(24)
  x0 += ks2; x1 += k0 + 2u;
  TF_R(13) TF_R(15) TF_R(26) TF_R(6)
  x0 += k0;  x1 += k1 + 3u;
  TF_R(17) TF_R(29) TF_R(16) TF_R(24)
  x0 += k1;  x1 += ks2 + 4u;
  TF_R(13) TF_R(15) TF_R(26) TF_R(6)
  x0 += ks2; x1 += k0 + 5u;
#undef TF_R
  TFOut o; o.a = x0; o.b = x1; return o;
}

// partitionable random_bits, 32-bit width, element index i (< 2^32)
__device__ static inline uint32_t rng_bits(uint32_t k0, uint32_t k1, uint32_t i) {
  TFOut r = tf2x32(k0, k1, 0u, i);
  return r.a ^ r.b;
}

__device__ static inline float bits_to_unit_float(uint32_t bits) {
  return __uint_as_float((bits >> 9) | 0x3F800000u) - 1.0f;
}

// XLA GenerateVF32Exp replica (cephes Horner port), mul+add separate,
// NO contraction.
__device__ static float xla_exp(float x_in) {
#pragma clang fp contract(off)
  float x = fminf(x_in, 88.3762626647950f);
  x = fmaxf(x, -88.3762626647949f);
  float fx = floorf(x * 1.44269504088896341f + 0.5f);
  float tmp = fx * 0.693359375f;
  float z = fx * -2.12194440e-4f;
  x = x - tmp;
  x = x - z;
  z = x * x;
  float y = 1.9875691500e-4f;
  y = y * x + 1.3981999507e-3f;
  y = y * x + 8.3334519073e-3f;
  y = y * x + 4.1665795894e-2f;
  y = y * x + 1.6666665459e-1f;
  y = y * x + 5.0000001201e-1f;
  y = y * z + x;
  y = y + 1.0f;
  int n = (int)fx;
  y = y * __uint_as_float((uint32_t)(n + 127) << 23);
  return y;
}

// XLA GenerateVF32Log replica = Pommier/Eigen3.3 log_ps (Horner + tail:
// y+=e*q1; y-=0.5*z; x+=y; x+=e*q2). NO contraction.
__device__ static float xla_log(float x_in) {
#pragma clang fp contract(off)
  float xv = fmaxf(x_in, 1.17549435e-38f);      // min_norm_pos clamp
  uint32_t bits = __float_as_uint(xv);
  float e = (float)((int)(bits >> 23) - 126);
  float x = __uint_as_float((bits & 0x007FFFFFu) | 0x3F000000u);  // [0.5,1)
  bool m = (x < 0.707106781186547524f);
  float tmp = m ? x : 0.0f;
  x = x - 1.0f;
  e = e - (m ? 1.0f : 0.0f);
  x = x + tmp;
  float z = x * x;
  float y = 7.0376836292e-2f;
  y = y * x + -1.1514610310e-1f;
  y = y * x + 1.1676998740e-1f;
  y = y * x + -1.2420140846e-1f;
  y = y * x + 1.4249322787e-1f;
  y = y * x + -1.6668057665e-1f;
  y = y * x + 2.0000714765e-1f;
  y = y * x + -2.4999993993e-1f;
  y = y * x + 3.3333331174e-1f;
  y = y * x;
  y = y * z;
  float t1 = e * -2.12194440e-4f;
  y = y + t1;
  float t2 = z * 0.5f;
  y = y - t2;
  x = x + y;
  float t3 = e * 0.693359375f;
  x = x + t3;
  return x;
}

// ---------------- kernels ----------------

__global__ void k_sentinel(float* out, float d) {
  out[0] = d;
}

// v0 one-hot (B,C,V) -> idx (B,V) u8
__global__ __launch_bounds__(256) void k_idx(const float* __restrict__ v0,
                                             uint8_t* __restrict__ idx) {
  int t = blockIdx.x * 256 + threadIdx.x;          // b*V + v
  int b = t >> 9, v = t & 511;
  const float* p = v0 + (size_t)b * (C_DIM * V_DIM) + v;
  int cf = 0;
#pragma unroll
  for (int c = 0; c < C_DIM; ++c)
    if (p[c * V_DIM] > 0.5f) cf = c;
  idx[t] = (uint8_t)cf;
}

// W (c,h,v) -> Wt (c,v,h)
__global__ __launch_bounds__(256) void k_wt(const float* __restrict__ W,
                                            float* __restrict__ Wt) {
  int t = blockIdx.x * 256 + threadIdx.x;          // (c, v, h)
  int h = t & 255; int rest = t >> 8; int v = rest & 511; int c = rest >> 9;
  Wt[t] = W[((size_t)c * H_DIM + h) * V_DIM + v];
}

// W (c,h,v) -> Wv (vt, c, h, v32): per-(vt,c) tile = contiguous 32 KB
__global__ __launch_bounds__(256) void k_wv(const float* __restrict__ W,
                                            float* __restrict__ Wv) {
  int f = blockIdx.x * 256 + threadIdx.x;   // ((vt*5+c)*256+h)*32+vl
  int vl = f & 31;
  int h  = (f >> 5) & 255;
  int r  = f >> 13;
  int c  = r % 5;
  int vt = r / 5;
  Wv[f] = W[((size_t)c * H_DIM + h) * V_DIM + vt * 32 + vl];
}

// h = bernoulli(sigmoid(kc-slab-folded k-ascending sum + c1))
// In-LDS compaction (round 7): soff[512] = selected k offsets asc,
// jb[s] = kc-panel boundaries. Order bit-identical to round 6.
__global__ __launch_bounds__(256) void k_sample_h(
    const float* __restrict__ Wt, const float* __restrict__ c1,
    const uint8_t* __restrict__ idx,
    float* __restrict__ out_h, uint32_t* __restrict__ out_mask,
    uint32_t key0, uint32_t key1) {
  __shared__ uint8_t  sidx[V_DIM];
  __shared__ uint32_t soff[V_DIM];     // (c*512+v)*1024 byte offsets, k asc
  __shared__ uint16_t cnt[8][5];       // per 64-lane segment, per class
  __shared__ uint16_t base[8][5];      // global start position
  __shared__ uint16_t jb[10];          // panel boundaries in j-space
  int b = blockIdx.x;
  int t = threadIdx.x;
  if (t < 128)
    ((uint32_t*)sidx)[t] = ((const uint32_t*)(idx + (size_t)b * V_DIM))[t];
  __syncthreads();

  int lane = t & 63, wv = t >> 6;
  int v0 = t,       c0 = sidx[v0];
  int v1 = t + 256, c1i = sidx[v1];
  int rank0, rank1;
  {
    unsigned long long bal[5];
#pragma unroll
    for (int cc = 0; cc < 5; ++cc) bal[cc] = __ballot(c0 == cc);
    if (lane == 0) {
#pragma unroll
      for (int cc = 0; cc < 5; ++cc) cnt[wv][cc] = (uint16_t)__popcll(bal[cc]);
    }
    rank0 = (int)__popcll(bal[c0] & ((1ull << lane) - 1ull));
  }
  {
    unsigned long long bal[5];
#pragma unroll
    for (int cc = 0; cc < 5; ++cc) bal[cc] = __ballot(c1i == cc);
    if (lane == 0) {
#pragma unroll
      for (int cc = 0; cc < 5; ++cc) cnt[4 + wv][cc] = (uint16_t)__popcll(bal[cc]);
    }
    rank1 = (int)__popcll(bal[c1i] & ((1ull << lane) - 1ull));
  }
  __syncthreads();
  if (t == 0) {
    int pos = 0;
    for (int cc = 0; cc < 5; ++cc)
      for (int g = 0; g < 8; ++g) { base[g][cc] = (uint16_t)pos; pos += cnt[g][cc]; }
  }
  __syncthreads();
  soff[base[wv][c0] + rank0]       = (uint32_t)(c0 * V_DIM + v0) << 10;   // k*1024B
  soff[base[4 + wv][c1i] + rank1]  = (uint32_t)(c1i * V_DIM + v1) << 10;
  __syncthreads();
  if (t < 10) {
    uint32_t target = (uint32_t)(t * KC) << 10;
    int lo = 0, hi = V_DIM;
    while (lo < hi) { int mid = (lo + hi) >> 1;
      if (soff[mid] < target) lo = mid + 1; else hi = mid; }
    jb[t] = (uint16_t)lo;
  }
  __syncthreads();

  // main accumulation: h = t
  const char* Wh = (const char*)Wt + (size_t)t * 4;
  float total = 0.0f;
  for (int s = 0; s < 9; ++s) {
    int j = jb[s], jend = jb[s + 1];
    float psum = 0.0f;
    for (; j + 4 <= jend; j += 4) {
      float w0 = *(const float*)(Wh + soff[j]);
      float w1 = *(const float*)(Wh + soff[j + 1]);
      float w2 = *(const float*)(Wh + soff[j + 2]);
      float w3 = *(const float*)(Wh + soff[j + 3]);
      psum += w0; psum += w1; psum += w2; psum += w3;
    }
    for (; j < jend; ++j) psum += *(const float*)(Wh + soff[j]);
    total += psum;
  }

  float tt = total + c1[t];
  float p = 1.0f / (1.0f + xla_exp(-tt));   // IEEE div, logistic exp form

  uint32_t i = (uint32_t)(b * H_DIM + t);
  float u = bits_to_unit_float(rng_bits(key0, key1, i));
  bool hb = (u < p);
  if (out_h) out_h[(size_t)b * H_DIM + t] = hb ? 1.0f : 0.0f;

  unsigned long long m = __ballot(hb);
  if ((t & 63) == 0) {
    out_mask[(size_t)b * 8 + wv * 2 + 0] = (uint32_t)(m & 0xFFFFFFFFull);
    out_mask[(size_t)b * 8 + wv * 2 + 1] = (uint32_t)(m >> 32);
  }
}

// v = categorical over c of (sum_{set h asc} W[c,h,v] + b2 + gumbel).
// BT=128 b's share each contiguous 32 KB (c,vt) L1 tile. Per-b h-list
// compacted to LDS (uint8, stride 260). Order bit-identical.
__global__ __launch_bounds__(1024) void k_sample_v(
    const float* __restrict__ Wv, const float* __restrict__ b2,
    const uint32_t* __restrict__ mask, uint8_t* __restrict__ idx_out,
    uint32_t key0, uint32_t key1) {
  __shared__ uint8_t  hl[BT * 260];     // per-b ascending set-h list
  __shared__ uint16_t cnts[BT][8];
  __shared__ uint16_t nselS[BT];
  int tid = threadIdx.x;
  int vt = blockIdx.x & 15;             // mod-16: co-resident blocks share vt
  int bb = blockIdx.x >> 4;
  int b0 = bb * BT;

  // phase 1: compact masks (128 b x 8 u32-chunks)
  {
    int bl = tid >> 3, ch = tid & 7;
    uint32_t w = mask[(size_t)b0 * 8 + tid];   // coalesced
    cnts[bl][ch] = (uint16_t)__popc(w);
    __syncthreads();
    int pre = 0;
    for (int k = 0; k < ch; ++k) pre += cnts[bl][k];
    uint8_t* row = hl + bl * 260;
    int hb = ch * 32, pos = pre;
    uint32_t ww = w;
    while (ww) {
      int bit = __ffs(ww) - 1;
      row[pos++] = (uint8_t)(hb + bit);
      ww &= ww - 1;
    }
    if (ch == 7) nselS[bl] = (uint16_t)(pre + __popc(w));
  }
  __syncthreads();

  int bl = tid >> 3;                    // 0..127
  int vq = tid & 7;                     // v-quad within 32-v tile
  int n  = nselS[bl];
  const uint32_t* hrow = (const uint32_t*)(hl + bl * 260);
  const float* Wbase = Wv + (size_t)(vt * 5) * 8192;   // 256*32 per (vt,c)

  float a[C_DIM][4];
#pragma unroll
  for (int c = 0; c < C_DIM; ++c)
    { a[c][0] = 0.f; a[c][1] = 0.f; a[c][2] = 0.f; a[c][3] = 0.f; }

  for (int c = 0; c < C_DIM; ++c) {
    const float* Wc = Wbase + (size_t)c * 8192 + vq * 4;
    float s0 = 0.f, s1 = 0.f, s2 = 0.f, s3 = 0.f;
    for (int j = 0; j < n; j += 4) {
      uint32_t hw = hrow[j >> 2];
#pragma unroll
      for (int k = 0; k < 4; ++k) {
        if (j + k < n) {
          int h = (hw >> (8 * k)) & 255;
          const float4 w4 = *(const float4*)(Wc + h * 32);
          s0 += w4.x; s1 += w4.y; s2 += w4.z; s3 += w4.w;
        }
      }
    }
    a[c][0] = s0; a[c][1] = s1; a[c][2] = s2; a[c][3] = s3;
    __syncthreads();   // keep the block's waves on the same (c,vt) L1 tile
  }

  // epilogue: gumbel + first-max argmax over c (ascending), 4 v's
  int b = b0 + bl;
  int v0 = vt * 32 + vq * 4;
  float best[4]; int bc[4];
#pragma unroll
  for (int q = 0; q < 4; ++q) { best[q] = 0.f; bc[q] = 0; }
#pragma unroll
  for (int c = 0; c < C_DIM; ++c) {
    uint32_t ibase = ((uint32_t)b * C_DIM + c) * V_DIM + (uint32_t)v0;
#pragma unroll
    for (int q = 0; q < 4; ++q) {
      float uf = bits_to_unit_float(rng_bits(key0, key1, ibase + q));
      if (uf == 0.0f) uf = 1.17549435e-38f;        // u + tiny semantics
      float g = -xla_log(-xla_log(uf));
      float z = g + (a[c][q] + b2[c * V_DIM + v0 + q]);
      if (c == 0 || z > best[q]) { best[q] = z; bc[q] = c; }
    }
  }
  uint32_t pack = (uint32_t)bc[0] | ((uint32_t)bc[1] << 8) |
                  ((uint32_t)bc[2] << 16) | ((uint32_t)bc[3] << 24);
  *(uint32_t*)(idx_out + (size_t)b * V_DIM + v0) = pack;
}

// idx -> one-hot f32 (B,C,V)
__global__ __launch_bounds__(256) void k_onehot(const uint8_t* __restrict__ idx,
                                                float* __restrict__ out) {
  int t = blockIdx.x * 256 + threadIdx.x;     // b*C*V + c*V + v
  int v = t & 511; int rest = t >> 9; int c = rest % C_DIM; int b = rest / C_DIM;
  out[t] = (idx[(size_t)b * V_DIM + v] == c) ? 1.0f : 0.0f;
}

// ---------------- launch ----------------

extern "C" void kernel_launch(void* const* d_in, const int* in_sizes, int n_in,
                              void* d_out, int out_size, void* d_ws, size_t ws_size,
                              hipStream_t stream) {
  float* out = (float*)d_out;

  // ---- structural sentinels ----
  const size_t WS_NEED = 2621440ull      // Wt
                       + 2621440ull      // Wv
                       + 8388608ull      // idx
                       + 524288ull;      // mask  = 14,155,776 B
  float D = 0.0f;
  if (n_in < 4)                       D = 910.0f + (float)n_in;
  else if (in_sizes[0] != 41943040)   D = 920.0f;
  else if (in_sizes[1] != 655360)     D = 921.0f;
  else if (in_sizes[2] != 2560)       D = 922.0f;
  else if (in_sizes[3] != 256)        D = 923.0f;
  else if (out_size != 50331648)      D = 930.0f + (float)out_size * 1e-6f;
  else if (ws_size < WS_NEED)         D = 100.0f + (float)(ws_size >> 20);
  if (D != 0.0f) {
    hipLaunchKernelGGL(k_sentinel, dim3(1), dim3(1), 0, stream, out, D);
    return;
  }

  const float* v0 = (const float*)d_in[0];
  const float* W  = (const float*)d_in[1];
  const float* b2 = (const float*)d_in[2];   // (C,V)
  const float* c1 = (const float*)d_in[3];   // (H)

  float* out_v  = out;                                         // B*C*V
  float* out_h  = out + (size_t)B_DIM * C_DIM * V_DIM;         // B*H (final h)
  float* out_h0 = out_h + (size_t)B_DIM * H_DIM;               // B*H (h|v0)

  char* ws = (char*)d_ws;
  float*    Wt   = (float*)(ws);                    // 2,621,440 B
  float*    Wv   = (float*)(ws + 2621440);          // 2,621,440 B
  uint8_t*  idx  = (uint8_t*)(ws + 5242880);        // 8,388,608 B
  uint32_t* mask = (uint32_t*)(ws + 13631488);      //   524,288 B

  // partitionable (fold-like) split of key(42) into 5 subkeys
  uint32_t keys[5][2];
  for (int i = 0; i < 5; ++i) {
    TFOut r = tf2x32(0u, 42u, 0u, (uint32_t)i);
    keys[i][0] = r.a; keys[i][1] = r.b;
  }

  hipLaunchKernelGGL(k_wt,  dim3(2560),  dim3(256), 0, stream, W, Wt);
  hipLaunchKernelGGL(k_wv,  dim3(2560),  dim3(256), 0, stream, W, Wv);
  hipLaunchKernelGGL(k_idx, dim3(32768), dim3(256), 0, stream, v0, idx);

  // h0 = sample_h(keys[0], v0) -> h_given_v0 output + mask
  hipLaunchKernelGGL(k_sample_h, dim3(B_DIM), dim3(256), 0, stream,
                     Wt, c1, idx, out_h0, mask, keys[0][0], keys[0][1]);
  // iter 0: v = sample_v(keys[1], h0); h1 = sample_h(keys[2], v)
  hipLaunchKernelGGL(k_sample_v, dim3((B_DIM / BT) * 16), dim3(1024), 0, stream,
                     Wv, b2, mask, idx, keys[1][0], keys[1][1]);
  hipLaunchKernelGGL(k_sample_h, dim3(B_DIM), dim3(256), 0, stream,
                     Wt, c1, idx, (float*)nullptr, mask, keys[2][0], keys[2][1]);
  // iter 1: v = sample_v(keys[3], h1); h2 = sample_h(keys[4], v)
  hipLaunchKernelGGL(k_sample_v, dim3((B_DIM / BT) * 16), dim3(1024), 0, stream,
                     Wv, b2, mask, idx, keys[3][0], keys[3][1]);
  hipLaunchKernelGGL(k_sample_h, dim3(B_DIM), dim3(256), 0, stream,
                     Wt, c1, idx, out_h, mask, keys[4][0], keys[4][1]);
  // final v one-hot output
  hipLaunchKernelGGL(k_onehot, dim3(163840), dim3(256), 0, stream, idx, out_v);
}